// Round 18
// baseline (116.088 us; speedup 1.0000x reference)
//
#include <hip/hip_runtime.h>

#define NPIX  65536
#define NG    512
#define NB    4
#define MAXD  362.03867196751236f
#define WRAD  16                  // term-2 Chebyshev window radius
#define WDIM  33                  // 2*WRAD+1
#define WCNT  1089                // WDIM*WDIM
#define SAFE_Q (15.0f - MAXD)     // window min <= this => provably global
#define NBLK  512                 // homogeneous: each block = T1(2 rows) + T2(4 pts)
#define BRAD  32                  // term-1 row-band radius
#define BSPAN 66                  // gh in [hp-32, hp+33]
#define BCAP  256                 // band capacity (mean 132, sd ~10)

// ws layout (floats):
//   [0,   512) : term-1 per-block sum p*min_d   (img = blk>>7)
//   [512, 1024): term-1 per-block sum p
//   [1024,3072): per-(b,g) min of p*(d - MAXD)

__device__ __forceinline__ float wave_sum(float v){
  #pragma unroll
  for (int o = 32; o > 0; o >>= 1) v += __shfl_down(v, o, 64);
  return v;
}
__device__ __forceinline__ float wave_min(float v){
  #pragma unroll
  for (int o = 32; o > 0; o >>= 1) v = fminf(v, __shfl_down(v, o, 64));
  return v;
}

__global__ __launch_bounds__(256) void k_all(const float* __restrict__ prob,
                                             const int* __restrict__ gt,
                                             float* __restrict__ ws){
  const int tid  = threadIdx.x;
  const int lane = tid & 63;
  const int wv   = tid >> 6;
  __shared__ float2 gsab[NG];        // full gt (fallback path)
  __shared__ float2 bsab[BCAP + 1];  // band list + sentinel
  __shared__ float red[8];
  __shared__ int bcnt, ovf, anybad;

  const int j  = blockIdx.x;
  const int b  = j >> 7;             // 128 blocks per image
  const int hp = (j & 127) << 1;     // rows hp, hp+1

  if (tid == 0){ bcnt = 0; ovf = 0; anybad = 0; }
  __syncthreads();

  // ---- stage gt + ballot-compact row-band (8 LDS atomics total) ----
  const int2* gtp = ((const int2*)gt) + b*NG;
  #pragma unroll
  for (int s = 0; s < 2; ++s){
    const int g = tid + 256*s;
    const int2 q = gtp[g];
    const float2 v2 = make_float2(-2.0f*(float)q.x, -2.0f*(float)q.y);
    gsab[g] = v2;
    const bool in = ((unsigned)(q.x - (hp - BRAD)) < (unsigned)BSPAN);
    const unsigned long long mk = __ballot(in);
    int base = 0;
    if (lane == 0) base = atomicAdd(&bcnt, __popcll(mk));
    base = __shfl(base, 0, 64);
    if (in){
      const int pos = base + (int)__popcll(mk & ((1ULL << lane) - 1ULL));
      if (pos < BCAP) bsab[pos] = v2; else ovf = 1;
    }
  }
  __syncthreads();
  const int Lc = min(bcnt, BCAP);
  if (tid == 0) bsab[Lc] = make_float2(-20000.0f, -20000.0f);  // sentinel (d2 ~ 2e8)
  __syncthreads();

  // ---- term-1: band scan, 2 rows, thread = column ----
  const float wf  = (float)tid;
  const float hf0 = (float)hp, hf1 = (float)(hp + 1);
  float m0 = 3e38f, m1 = 3e38f;
  const int pairs = (Lc + 1) >> 1;
  #pragma unroll 2
  for (int k = 0; k < pairs; ++k){
    const float2 q0 = bsab[2*k + 0];               // wave-uniform broadcast
    const float2 q1 = bsab[2*k + 1];
    const float sc0 = fmaf(q0.y, q0.y, q0.x*q0.x) * 0.25f;  // gh^2+gw^2, exact
    const float sc1 = fmaf(q1.y, q1.y, q1.x*q1.x) * 0.25f;
    const float u0  = fmaf(q0.y, wf, sc0);         // sc - 2gw*w, exact int
    const float u1  = fmaf(q1.y, wf, sc1);
    const float t00 = fmaf(q0.x, hf0, u0);         // d2 - (h^2+w^2), exact int
    const float t10 = fmaf(q1.x, hf0, u1);
    m0 = fminf(fminf(m0, t00), t10);               // v_min3
    const float t01 = fmaf(q0.x, hf1, u0);
    const float t11 = fmaf(q1.x, hf1, u1);
    m1 = fminf(fminf(m1, t01), t11);
  }

  // certification: out-of-band => d2 >= 1089 > 1024 (exact ints)
  const float w2 = (float)(tid*tid);
  float v0 = m0 + fmaf(hf0, hf0, w2);
  float v1 = m1 + fmaf(hf1, hf1, w2);
  if (ovf || (v0 > 1024.0f) || (v1 > 1024.0f)) anybad = 1;   // benign race
  __syncthreads();

  if (anybad){
    // exact fallback: full 512-point scan (block-uniform; ~never on real data)
    m0 = 3e38f; m1 = 3e38f;
    #pragma unroll 4
    for (int k = 0; k < 256; ++k){
      const float2 q0 = gsab[2*k + 0];
      const float2 q1 = gsab[2*k + 1];
      const float sc0 = fmaf(q0.y, q0.y, q0.x*q0.x) * 0.25f;
      const float sc1 = fmaf(q1.y, q1.y, q1.x*q1.x) * 0.25f;
      const float u0  = fmaf(q0.y, wf, sc0);
      const float u1  = fmaf(q1.y, wf, sc1);
      const float t00 = fmaf(q0.x, hf0, u0);
      const float t10 = fmaf(q1.x, hf0, u1);
      m0 = fminf(fminf(m0, t00), t10);
      const float t01 = fmaf(q0.x, hf1, u0);
      const float t11 = fmaf(q1.x, hf1, u1);
      m1 = fminf(fminf(m1, t01), t11);
    }
    v0 = m0 + fmaf(hf0, hf0, w2);
    v1 = m1 + fmaf(hf1, hf1, w2);
  }

  const float p0 = prob[b*NPIX + hp*256 + tid];          // coalesced
  const float p1 = prob[b*NPIX + hp*256 + 256 + tid];
  float spd = fmaf(p0, __builtin_amdgcn_sqrtf(v0), p1 * __builtin_amdgcn_sqrtf(v1));
  float sp  = p0 + p1;
  spd = wave_sum(spd);
  sp  = wave_sum(sp);
  if (lane == 0){ red[wv] = spd; red[4+wv] = sp; }
  __syncthreads();
  if (tid == 0){
    ws[j]       = (red[0]+red[1]) + (red[2]+red[3]);
    ws[512 + j] = (red[4]+red[5]) + (red[6]+red[7]);
  }

  // ---- term-2: 4 points per block, one per wave ----
  const int idx = j*4 + wv;          // 0..2047 = b2*NG + g
  const int b2  = idx >> 9;
  const int gh  = gt[idx*2 + 0];     // wave-uniform
  const int gw  = gt[idx*2 + 1];

  float qm = 3e38f;
  for (int i = lane; i < WCNT; i += 64){
    const int r  = i / WDIM;
    const int c  = i - r*WDIM;
    const int hh = gh - WRAD + r;
    const int ww = gw - WRAD + c;
    if ((unsigned)hh < 256u && (unsigned)ww < 256u){
      const float p  = prob[b2*NPIX + hh*256 + ww];
      const int  dh  = r - WRAD, dw = c - WRAD;
      const float d  = __builtin_amdgcn_sqrtf((float)(dh*dh + dw*dw));
      qm = fminf(qm, fmaf(p, d, p * (-MAXD)));
    }
  }
  qm = wave_min(qm);
  qm = __shfl(qm, 0, 64);            // broadcast for uniform branch

  if (qm > SAFE_Q){
    // exact fallback: this wave rescans the full image (rare; keeps kernel exact)
    const float ghf = (float)gh, gwf = (float)gw;
    float q2 = 3e38f;
    for (int i = lane; i < NPIX; i += 64){
      const int hh = i >> 8, ww = i & 255;
      const float dh = (float)hh - ghf, dw = (float)ww - gwf;
      const float d  = __builtin_amdgcn_sqrtf(fmaf(dh, dh, dw*dw));
      const float p  = prob[b2*NPIX + i];
      q2 = fminf(q2, fmaf(p, d, p * (-MAXD)));
    }
    q2 = wave_min(q2);
    qm = q2;
  }
  if (lane == 0) ws[1024 + idx] = qm;
}

// ---------- finish: fully parallel deterministic reduction ----------
__global__ __launch_bounds__(256) void k_finish(const float* __restrict__ ws,
                                                float* __restrict__ out){
  const int tid  = threadIdx.x;
  const int w    = tid >> 6;        // wave id == image id
  const int lane = tid & 63;
  __shared__ float redT2[4];
  __shared__ float t1sh[NB];

  // term-2 sum: 2048 values, 8 per thread, coalesced
  float s = 0.0f;
  #pragma unroll
  for (int jj = 0; jj < 8; ++jj) s += ws[1024 + tid*8 + jj];
  s = wave_sum(s);
  if (lane == 0) redT2[w] = s;

  // term-1: wave w = image w; 128 pd + 128 pp partials, 2 each per lane
  float pd = ws[w*128 + lane] + ws[w*128 + 64 + lane];
  float pp = ws[512 + w*128 + lane] + ws[512 + w*128 + 64 + lane];
  pd = wave_sum(pd);
  pp = wave_sum(pp);
  if (lane == 0) t1sh[w] = pd / (pp + 1e-6f);
  __syncthreads();

  if (tid == 0){
    const float s2    = (redT2[0]+redT2[1]) + (redT2[2]+redT2[3]);
    const float term2 = MAXD + s2 * (1.0f/2048.0f);
    const float term1 = ((t1sh[0]+t1sh[1]) + (t1sh[2]+t1sh[3])) * 0.25f;
    out[0] = term1 + term2;
  }
}

extern "C" void kernel_launch(void* const* d_in, const int* in_sizes, int n_in,
                              void* d_out, int out_size, void* d_ws, size_t ws_size,
                              hipStream_t stream) {
  const float* prob = (const float*)d_in[0];
  const int*   gt   = (const int*)d_in[1];
  float* out = (float*)d_out;
  float* ws  = (float*)d_ws;

  hipLaunchKernelGGL(k_all,    dim3(NBLK), dim3(256), 0, stream, prob, gt, ws);
  hipLaunchKernelGGL(k_finish, dim3(1),    dim3(256), 0, stream, ws, out);
}

// Round 19
// 16.420 us; speedup vs baseline: 7.0697x; 7.0697x over previous
//
#include <hip/hip_runtime.h>

#define NPIX  65536
#define NG    512
#define NB    4
#define MAXD  362.03867196751236f
#define WRAD  24                  // term-2 Chebyshev window radius (P(fallback) ~ e^-35: never)
#define WDIM  49                  // 2*WRAD+1
#define WCNT  2401                // WDIM*WDIM
#define SAFE_Q (23.0f - MAXD)     // window min <= this => provably global
#define NBLK_T1 128               // term-1: 8 rows per block
#define NBLK_T2 (NB*NG)           // 2048
#define NBLK_MAIN (NBLK_T1 + NBLK_T2)
#define BRAD 32                   // term-1 row-band radius: out-of-band => d > 32
#define BSPAN 72                  // band rows: [hp-32, hp+39]
#define BCAP 352                  // band list capacity (mean 144, sd 10 -> P(overflow)~0)

// ws layout (floats):
//   [0,   128) : term-1 per-block partial sum of p*min_d   (img = blk>>5)
//   [512, 640) : term-1 per-block partial sum of p
//   [1024,3072): per-(b,g) min of p*(d - MAXD)

__device__ __forceinline__ float wave_sum(float v){
  #pragma unroll
  for (int o = 32; o > 0; o >>= 1) v += __shfl_down(v, o, 64);
  return v;
}
__device__ __forceinline__ float wave_min(float v){
  #pragma unroll
  for (int o = 32; o > 0; o >>= 1) v = fminf(v, __shfl_down(v, o, 64));
  return v;
}

// ---------- main: term-1 (blocks 0..127) + term-2 windows (blocks 128..2175) ----------
__global__ __launch_bounds__(256) void k_main(const float* __restrict__ prob,
                                              const int* __restrict__ gt,
                                              float* __restrict__ wsout){
  const int tid = threadIdx.x;

  if (blockIdx.x < NBLK_T1){
    // ----- term 1: block = (b, 8-row group); thread = column -----
    // Row-band pruning: only gt with gh in [hp-32, hp+39] tested (exp ~144/512).
    // Certified iff band-min d2 <= 1024 (out-of-band => d2 > 1024, exact ints).
    // Any uncertified pixel (or list overflow) => full 512-point rescan (exact).
    __shared__ float2 gsab[NG];        // all 512 (fallback path)
    __shared__ float2 bsab[BCAP + 1];  // band list + sentinel slot
    __shared__ float red[8];
    __shared__ int bcnt, ovf, anybad;
    const int b  = blockIdx.x >> 5;                 // 32 blocks per image
    const int hp = (blockIdx.x & 31) << 3;          // rows hp .. hp+7
    const float wf = (float)tid;

    if (tid == 0){ bcnt = 0; ovf = 0; anybad = 0; }
    __syncthreads();

    const int2* gtp = ((const int2*)gt) + b*NG;
    #pragma unroll
    for (int s = 0; s < 2; ++s){
      const int g = tid + 256*s;
      const int2 q = gtp[g];
      const float2 v2 = make_float2(-2.0f*(float)q.x, -2.0f*(float)q.y);
      gsab[g] = v2;
      if ((unsigned)(q.x - (hp - BRAD)) < (unsigned)BSPAN){
        const int pos = atomicAdd(&bcnt, 1);
        if (pos < BCAP) bsab[pos] = v2; else ovf = 1;
      }
    }
    __syncthreads();
    const int Lc = min(bcnt, BCAP);
    if (tid == 0) bsab[Lc] = make_float2(-20000.0f, -20000.0f);  // sentinel (d2 ~ 2e8)
    __syncthreads();
    const int pairs = (Lc + 1) >> 1;

    float hf[8], m[8];
    #pragma unroll
    for (int r = 0; r < 8; ++r){ hf[r] = (float)(hp + r); m[r] = 3e38f; }

    #pragma unroll 2
    for (int k = 0; k < pairs; ++k){
      const float2 q0 = bsab[2*k + 0];              // wave-uniform broadcast
      const float2 q1 = bsab[2*k + 1];
      const float sc0 = fmaf(q0.y, q0.y, q0.x*q0.x) * 0.25f;  // gh^2+gw^2, exact
      const float sc1 = fmaf(q1.y, q1.y, q1.x*q1.x) * 0.25f;
      const float u0  = fmaf(q0.y, wf, sc0);        // sc - 2gw*w, exact int
      const float u1  = fmaf(q1.y, wf, sc1);
      #pragma unroll
      for (int r = 0; r < 8; ++r){
        const float t0 = fmaf(q0.x, hf[r], u0);     // d2 - (h^2+w^2), exact int
        const float t1 = fmaf(q1.x, hf[r], u1);
        m[r] = fminf(fminf(m[r], t0), t1);          // v_min3
      }
    }

    // certification: v[r] = true d2; uncertified if > 1024 (= BRAD^2)
    const float w2 = (float)(tid*tid);
    float v[8];
    int bad = ovf;
    #pragma unroll
    for (int r = 0; r < 8; ++r){
      v[r] = m[r] + fmaf(hf[r], hf[r], w2);
      bad |= (v[r] > 1024.0f);
    }
    if (bad) anybad = 1;                             // benign race
    __syncthreads();

    if (anybad){
      // exact fallback: full 512-point scan (block-uniform; ~never on real data)
      #pragma unroll
      for (int r = 0; r < 8; ++r) m[r] = 3e38f;
      #pragma unroll 4
      for (int k = 0; k < 256; ++k){
        const float2 q0 = gsab[2*k + 0];
        const float2 q1 = gsab[2*k + 1];
        const float sc0 = fmaf(q0.y, q0.y, q0.x*q0.x) * 0.25f;
        const float sc1 = fmaf(q1.y, q1.y, q1.x*q1.x) * 0.25f;
        const float u0  = fmaf(q0.y, wf, sc0);
        const float u1  = fmaf(q1.y, wf, sc1);
        #pragma unroll
        for (int r = 0; r < 8; ++r){
          const float t0 = fmaf(q0.x, hf[r], u0);
          const float t1 = fmaf(q1.x, hf[r], u1);
          m[r] = fminf(fminf(m[r], t0), t1);
        }
      }
      #pragma unroll
      for (int r = 0; r < 8; ++r) v[r] = m[r] + fmaf(hf[r], hf[r], w2);
    }

    float spd = 0.0f, sp = 0.0f;
    #pragma unroll
    for (int r = 0; r < 8; ++r){
      const float d = __builtin_amdgcn_sqrtf(v[r]);
      const float p = prob[b*NPIX + (hp + r)*256 + tid];   // coalesced
      spd = fmaf(p, d, spd);
      sp += p;
    }

    spd = wave_sum(spd);
    sp  = wave_sum(sp);
    const int wid = tid >> 6, lane = tid & 63;
    if (lane == 0){ red[wid] = spd; red[4+wid] = sp; }
    __syncthreads();
    if (tid == 0){
      wsout[blockIdx.x]       = (red[0]+red[1]) + (red[2]+red[3]);
      wsout[512 + blockIdx.x] = (red[4]+red[5]) + (red[6]+red[7]);
    }
  } else {
    // ----- term 2: one (b,g) per block; window + exact in-block fallback -----
    __shared__ float red[8];
    const int idx = blockIdx.x - NBLK_T1;           // b*NG + g
    const int b   = idx >> 9;
    const int gh  = gt[idx*2 + 0];
    const int gw  = gt[idx*2 + 1];

    float qm = 3e38f;
    for (int i = tid; i < WCNT; i += 256){
      const int r  = i / WDIM;
      const int c  = i - r*WDIM;
      const int hh = gh - WRAD + r;
      const int ww = gw - WRAD + c;
      if ((unsigned)hh < 256u && (unsigned)ww < 256u){
        const float p  = prob[b*NPIX + hh*256 + ww];
        const int  dh  = r - WRAD, dw = c - WRAD;
        const float d  = __builtin_amdgcn_sqrtf((float)(dh*dh + dw*dw));
        qm = fminf(qm, fmaf(p, d, p * (-MAXD)));
      }
    }
    qm = wave_min(qm);
    const int wid = tid >> 6, lane = tid & 63;
    if (lane == 0) red[wid] = qm;
    __syncthreads();
    float qf = fminf(fminf(red[0], red[1]), fminf(red[2], red[3]));

    if (qf > SAFE_Q){
      // exact fallback: full-image rescan, block-wide (rare; keeps kernel exact)
      const float ghf = (float)gh, gwf = (float)gw;
      const float aa  = -2.0f*ghf;
      const float wf  = (float)tid;
      const float bc  = fmaf(-2.0f*gwf, wf, fmaf(ghf, ghf, gwf*gwf));
      const float wsq = wf*wf;
      float q2 = 3e38f;
      const float* pr = prob + b*NPIX + tid;
      #pragma unroll 4
      for (int i = 0; i < 256; ++i){
        const float p   = pr[i*256];
        const float hfi = (float)i;
        const float d2v = fmaf(aa, hfi, fmaf(hfi, hfi, wsq) + bc);
        const float d   = __builtin_amdgcn_sqrtf(d2v);
        q2 = fminf(q2, fmaf(p, d, p * (-MAXD)));
      }
      q2 = wave_min(q2);
      __syncthreads();
      if (lane == 0) red[wid] = q2;
      __syncthreads();
      qf = fminf(fminf(red[0], red[1]), fminf(red[2], red[3]));
    }
    if (tid == 0) wsout[1024 + idx] = qf;
  }
}

// ---------- finish: fully parallel deterministic reduction ----------
__global__ __launch_bounds__(256) void k_finish(const float* __restrict__ ws,
                                                float* __restrict__ out){
  const int tid  = threadIdx.x;
  const int w    = tid >> 6;      // wave id == image id for term-1 part
  const int lane = tid & 63;
  __shared__ float redT2[4];
  __shared__ float t1sh[NB];

  // term-2 sum: 2048 values, 8 per thread, coalesced
  float s = 0.0f;
  #pragma unroll
  for (int j = 0; j < 8; ++j) s += ws[1024 + tid*8 + j];
  s = wave_sum(s);
  if (lane == 0) redT2[w] = s;

  // term-1: wave w = image w; lanes 0-31 carry pd partials, 32-63 carry pp
  float v = (lane < 32) ? ws[w*32 + lane] : ws[512 + w*32 + (lane - 32)];
  #pragma unroll
  for (int o = 16; o > 0; o >>= 1) v += __shfl_down(v, o, 32);
  const float ppv = __shfl(v, 32, 64);              // pp total (from lane 32)
  if (lane == 0) t1sh[w] = v / (ppv + 1e-6f);
  __syncthreads();

  if (tid == 0){
    const float s2    = (redT2[0]+redT2[1]) + (redT2[2]+redT2[3]);
    const float term2 = MAXD + s2 * (1.0f/2048.0f);
    const float term1 = ((t1sh[0]+t1sh[1]) + (t1sh[2]+t1sh[3])) * 0.25f;
    out[0] = term1 + term2;
  }
}

extern "C" void kernel_launch(void* const* d_in, const int* in_sizes, int n_in,
                              void* d_out, int out_size, void* d_ws, size_t ws_size,
                              hipStream_t stream) {
  const float* prob = (const float*)d_in[0];
  const int*   gt   = (const int*)d_in[1];
  float* out = (float*)d_out;
  float* ws  = (float*)d_ws;

  hipLaunchKernelGGL(k_main,   dim3(NBLK_MAIN), dim3(256), 0, stream, prob, gt, ws);
  hipLaunchKernelGGL(k_finish, dim3(1),         dim3(256), 0, stream, ws, out);
}

// Round 21
// 15.647 us; speedup vs baseline: 7.4192x; 1.0494x over previous
//
#include <hip/hip_runtime.h>

#define NPIX  65536
#define NG    512
#define NB    4
#define MAXD  362.03867196751236f
#define WRAD  24                  // term-2 Chebyshev window radius (P(fallback) ~ e^-35: never)
#define WDIM  49                  // 2*WRAD+1
#define WCNT  2401                // WDIM*WDIM
#define SAFE_Q (23.0f - MAXD)     // window min <= this => provably global
#define NBLK_T1 256               // term-1: 4 rows per block (1 block/CU)
#define NBLK_T2 (NB*NG)           // 2048
#define NBLK_MAIN (NBLK_T1 + NBLK_T2)
#define BRAD 32                   // term-1 row-band radius: out-of-band => d > 32
#define BSPAN 68                  // band rows: [hp-32, hp+35]
#define BCAP 320                  // band list capacity (mean 136, sd ~10 -> P(overflow)~0)

// ws layout (floats):
//   [0,   256) : term-1 per-block partial sum of p*min_d   (img = blk>>6)
//   [512, 768) : term-1 per-block partial sum of p
//   [1024,3072): per-(b,g) min of p*(d - MAXD)

__device__ __forceinline__ float wave_sum(float v){
  #pragma unroll
  for (int o = 32; o > 0; o >>= 1) v += __shfl_down(v, o, 64);
  return v;
}
__device__ __forceinline__ float wave_min(float v){
  #pragma unroll
  for (int o = 32; o > 0; o >>= 1) v = fminf(v, __shfl_down(v, o, 64));
  return v;
}

// ---------- main: term-1 (blocks 0..255) + term-2 windows (blocks 256..2303) ----------
__global__ __launch_bounds__(256) void k_main(const float* __restrict__ prob,
                                              const int* __restrict__ gt,
                                              float* __restrict__ wsout){
  const int tid = threadIdx.x;

  if (blockIdx.x < NBLK_T1){
    // ----- term 1: block = (b, 4-row group); thread = column -----
    // Row-band pruning: gt with gh in [hp-32, hp+35] (exp ~136/512).
    // Certified iff band-min d2 <= 1024 (out-of-band => d2 > 1024, exact ints).
    // Any uncertified pixel (or overflow) => full 512-point rescan (exact).
    __shared__ float2 gsab[NG];        // all 512 (fallback path)
    __shared__ float2 bsab[BCAP + 1];  // band list + sentinel
    __shared__ float red[8];
    __shared__ int bcnt, ovf, anybad;
    const int b  = blockIdx.x >> 6;                 // 64 blocks per image
    const int hp = (blockIdx.x & 63) << 2;          // rows hp .. hp+3
    const float wf = (float)tid;

    if (tid == 0){ bcnt = 0; ovf = 0; anybad = 0; }
    __syncthreads();

    const int2* gtp = ((const int2*)gt) + b*NG;
    #pragma unroll
    for (int s = 0; s < 2; ++s){
      const int g = tid + 256*s;
      const int2 q = gtp[g];
      const float2 v2 = make_float2(-2.0f*(float)q.x, -2.0f*(float)q.y);
      gsab[g] = v2;
      if ((unsigned)(q.x - (hp - BRAD)) < (unsigned)BSPAN){
        const int pos = atomicAdd(&bcnt, 1);
        if (pos < BCAP) bsab[pos] = v2; else ovf = 1;
      }
    }
    __syncthreads();
    const int Lc = min(bcnt, BCAP);
    if (tid == 0) bsab[Lc] = make_float2(-20000.0f, -20000.0f);  // sentinel (d2 ~ 2e8)
    __syncthreads();
    const int pairs = (Lc + 1) >> 1;

    float hf[4], m[4];
    #pragma unroll
    for (int r = 0; r < 4; ++r){ hf[r] = (float)(hp + r); m[r] = 3e38f; }

    #pragma unroll 4
    for (int k = 0; k < pairs; ++k){
      const float2 q0 = bsab[2*k + 0];              // wave-uniform broadcast
      const float2 q1 = bsab[2*k + 1];
      const float sc0 = fmaf(q0.y, q0.y, q0.x*q0.x) * 0.25f;  // gh^2+gw^2, exact
      const float sc1 = fmaf(q1.y, q1.y, q1.x*q1.x) * 0.25f;
      const float u0  = fmaf(q0.y, wf, sc0);        // sc - 2gw*w, exact int
      const float u1  = fmaf(q1.y, wf, sc1);
      #pragma unroll
      for (int r = 0; r < 4; ++r){
        const float t0 = fmaf(q0.x, hf[r], u0);     // d2 - (h^2+w^2), exact int
        const float t1 = fmaf(q1.x, hf[r], u1);
        m[r] = fminf(fminf(m[r], t0), t1);          // v_min3
      }
    }

    // certification: v[r] = true d2; uncertified if > 1024 (= BRAD^2)
    const float w2 = (float)(tid*tid);
    float v[4];
    int bad = ovf;
    #pragma unroll
    for (int r = 0; r < 4; ++r){
      v[r] = m[r] + fmaf(hf[r], hf[r], w2);
      bad |= (v[r] > 1024.0f);
    }
    if (bad) anybad = 1;                             // benign race
    __syncthreads();

    if (anybad){
      // exact fallback: full 512-point scan (block-uniform; ~never on real data)
      #pragma unroll
      for (int r = 0; r < 4; ++r) m[r] = 3e38f;
      #pragma unroll 4
      for (int k = 0; k < 256; ++k){
        const float2 q0 = gsab[2*k + 0];
        const float2 q1 = gsab[2*k + 1];
        const float sc0 = fmaf(q0.y, q0.y, q0.x*q0.x) * 0.25f;
        const float sc1 = fmaf(q1.y, q1.y, q1.x*q1.x) * 0.25f;
        const float u0  = fmaf(q0.y, wf, sc0);
        const float u1  = fmaf(q1.y, wf, sc1);
        #pragma unroll
        for (int r = 0; r < 4; ++r){
          const float t0 = fmaf(q0.x, hf[r], u0);
          const float t1 = fmaf(q1.x, hf[r], u1);
          m[r] = fminf(fminf(m[r], t0), t1);
        }
      }
      #pragma unroll
      for (int r = 0; r < 4; ++r) v[r] = m[r] + fmaf(hf[r], hf[r], w2);
    }

    float spd = 0.0f, sp = 0.0f;
    #pragma unroll
    for (int r = 0; r < 4; ++r){
      const float d = __builtin_amdgcn_sqrtf(v[r]);
      const float p = prob[b*NPIX + (hp + r)*256 + tid];   // coalesced
      spd = fmaf(p, d, spd);
      sp += p;
    }

    spd = wave_sum(spd);
    sp  = wave_sum(sp);
    const int wid = tid >> 6, lane = tid & 63;
    if (lane == 0){ red[wid] = spd; red[4+wid] = sp; }
    __syncthreads();
    if (tid == 0){
      wsout[blockIdx.x]       = (red[0]+red[1]) + (red[2]+red[3]);
      wsout[512 + blockIdx.x] = (red[4]+red[5]) + (red[6]+red[7]);
    }
  } else {
    // ----- term 2: one (b,g) per block; window + exact block-wide fallback -----
    __shared__ float red[8];
    const int idx = blockIdx.x - NBLK_T1;           // b*NG + g
    const int b   = idx >> 9;
    const int gh  = gt[idx*2 + 0];
    const int gw  = gt[idx*2 + 1];

    float qm = 3e38f;
    for (int i = tid; i < WCNT; i += 256){
      const int r  = i / WDIM;
      const int c  = i - r*WDIM;
      const int hh = gh - WRAD + r;
      const int ww = gw - WRAD + c;
      if ((unsigned)hh < 256u && (unsigned)ww < 256u){
        const float p  = prob[b*NPIX + hh*256 + ww];
        const int  dh  = r - WRAD, dw = c - WRAD;
        const float d  = __builtin_amdgcn_sqrtf((float)(dh*dh + dw*dw));
        qm = fminf(qm, fmaf(p, d, p * (-MAXD)));
      }
    }
    qm = wave_min(qm);
    const int wid = tid >> 6, lane = tid & 63;
    if (lane == 0) red[wid] = qm;
    __syncthreads();
    float qf = fminf(fminf(red[0], red[1]), fminf(red[2], red[3]));

    if (qf > SAFE_Q){
      // exact fallback: full-image rescan, BLOCK-wide (rare; keeps kernel exact)
      const float ghf = (float)gh, gwf = (float)gw;
      const float aa  = -2.0f*ghf;
      const float wf  = (float)tid;
      const float bc  = fmaf(-2.0f*gwf, wf, fmaf(ghf, ghf, gwf*gwf));
      const float wsq = wf*wf;
      float q2 = 3e38f;
      const float* pr = prob + b*NPIX + tid;
      #pragma unroll 4
      for (int i = 0; i < 256; ++i){
        const float p   = pr[i*256];
        const float hfi = (float)i;
        const float d2v = fmaf(aa, hfi, fmaf(hfi, hfi, wsq) + bc);
        const float d   = __builtin_amdgcn_sqrtf(d2v);
        q2 = fminf(q2, fmaf(p, d, p * (-MAXD)));
      }
      q2 = wave_min(q2);
      __syncthreads();
      if (lane == 0) red[wid] = q2;
      __syncthreads();
      qf = fminf(fminf(red[0], red[1]), fminf(red[2], red[3]));
    }
    if (tid == 0) wsout[1024 + idx] = qf;
  }
}

// ---------- finish: fully parallel deterministic reduction ----------
__global__ __launch_bounds__(256) void k_finish(const float* __restrict__ ws,
                                                float* __restrict__ out){
  const int tid  = threadIdx.x;
  const int w    = tid >> 6;      // wave id == image id
  const int lane = tid & 63;
  __shared__ float redT2[4];
  __shared__ float t1sh[NB];

  // term-2 sum: 2048 values, 8 per thread, coalesced
  float s = 0.0f;
  #pragma unroll
  for (int j = 0; j < 8; ++j) s += ws[1024 + tid*8 + j];
  s = wave_sum(s);
  if (lane == 0) redT2[w] = s;

  // term-1: wave w = image w; 64 pd + 64 pp partials, one per lane
  float pd = ws[w*64 + lane];
  float pp = ws[512 + w*64 + lane];
  pd = wave_sum(pd);
  pp = wave_sum(pp);
  if (lane == 0) t1sh[w] = pd / (pp + 1e-6f);
  __syncthreads();

  if (tid == 0){
    const float s2    = (redT2[0]+redT2[1]) + (redT2[2]+redT2[3]);
    const float term2 = MAXD + s2 * (1.0f/2048.0f);
    const float term1 = ((t1sh[0]+t1sh[1]) + (t1sh[2]+t1sh[3])) * 0.25f;
    out[0] = term1 + term2;
  }
}

extern "C" void kernel_launch(void* const* d_in, const int* in_sizes, int n_in,
                              void* d_out, int out_size, void* d_ws, size_t ws_size,
                              hipStream_t stream) {
  const float* prob = (const float*)d_in[0];
  const int*   gt   = (const int*)d_in[1];
  float* out = (float*)d_out;
  float* ws  = (float*)d_ws;

  hipLaunchKernelGGL(k_main,   dim3(NBLK_MAIN), dim3(256), 0, stream, prob, gt, ws);
  hipLaunchKernelGGL(k_finish, dim3(1),         dim3(256), 0, stream, ws, out);
}